// Round 13
// baseline (257.074 us; speedup 1.0000x reference)
//
#include <hip/hip_runtime.h>

// Problem: VOCAB=10000, EMB=100, T=80, UNITS=256, BATCH=4096 — ALL FP32 I/O.
// out = sigmoid(h2_T);  h_l,t = tanh(x_l,t @ Wl + h_l,t-1 @ Ul + bl)
//
// v18 theory (from v17 counters): LDS pipe still the largest term
// (216 KB/CU-iter ~ 2540cy of 4370); biggest removable chunk = u2b stream
// (64 KB/CU-iter of loop-invariant weights). v16 proved global/L2 works
// mechanically but spilled because ub[8] (32 regs) was forced live atop
// 160 pins + dual-y accs. v18 fixes the pressure on both ends:
//  - y chains merged (yA+yB -> single y per tile): -8 regs, -8 adds; still
//    4 indep chains/wave (x0,x1,y0,y1) x 2 waves/SIMD = 8 in flight.
//  - ub frag loaded AT ITS USE POINT in the unrolled kt loop: the pressure-
//    aware scheduler hoists a few, not all 8 (v16 forced all live).
//    Est. live ~215 vs v15-clean ~208 / v16-spilled ~240.
//  - u2s LDS buffer + dynamic LDS deleted; lgkm-only barrier lets the
//    L2-hot u2b loads (same 64 KB of lines every iter) pipeline across iters.
// Rest byte-identical to v17 (swapped-operand MFMA, 160-reg "+v" pin,
// P1 b128 staging, rcp-tanh, compile-time buffer indices).
// Tripwire: WRITE_SIZE must stay 4.1 MB; if not, revert to v17.
#define BATCH 4096
#define TLEN  80
#define EMBD  100
#define UNITS 256

typedef _Float16 f16;
typedef __attribute__((ext_vector_type(8))) _Float16 h8;   // 8 f16 = 4 VGPR MFMA A/B frag
typedef __attribute__((ext_vector_type(4))) _Float16 h4;   // 4 f16 = b64
typedef __attribute__((ext_vector_type(4))) float f32x4;   // MFMA C/D frag

// tanh(x) = sign(x) * (1-e)/(1+e), e = exp(-2|x|) in (0,1].
__device__ __forceinline__ float fast_tanh(float x) {
  float ax = __builtin_fabsf(x);
  float e  = __expf(-2.f * ax);
  float r  = (1.f - e) * __builtin_amdgcn_rcpf(1.f + e);
  return __builtin_copysignf(r, x);
}
// sigmoid(x) = rcp(1 + exp(-x)); saturates correctly at both ends.
__device__ __forceinline__ float fast_sigmoid(float x) {
  return __builtin_amdgcn_rcpf(1.f + __expf(-x));
}

// LDS-only barrier: all prior LDS ops visible, but vmcnt NOT drained.
__device__ __forceinline__ void block_sync_lds() {
  asm volatile("s_waitcnt lgkmcnt(0)\n\ts_barrier" ::: "memory");
}

// ---------------- workspace layout (5.58 MB <= 6.04 MB proven available) ---
// P1 table: 10000 x 256 f16 = 5,120,000 B.  wf frags: 458,752 B.
// B-frag layout (16x16x32, r7-verified): lane holds B[k=quad*8+j][n=lane&15].
// ktg slots: W1 = 0..3 (unused by main), U1 = 4..11, W2 = 12..19, U2 = 20..27.
#define KT_ALL 28
#define OFF_P1 ((size_t)0)
#define P1_BYTES ((size_t)10000 * UNITS * 2)                // 5,120,000
#define OFF_WF  P1_BYTES
#define WF_BYTES ((size_t)KT_ALL * 16 * 64 * 8 * 2)         //   458,752
#define WS_NEED (OFF_WF + WF_BYTES)                          // 5,578,752 B

__device__ __forceinline__ size_t fidx(int ktg, int nt, int lane) {
  return (((size_t)ktg * 16 + nt) * 64 + lane) * 8;
}

// ---------------- precompute: weights -> swizzled fp16 B-frags (r10-verified)
__global__ __launch_bounds__(256) void k_split_w16(
    const float* __restrict__ W1, const float* __restrict__ U1,
    const float* __restrict__ W2, const float* __restrict__ U2,
    f16* __restrict__ wf)
{
  int gid = blockIdx.x * 256 + threadIdx.x;           // one per (ktg,nt,lane)
  if (gid >= KT_ALL * 16 * 64) return;
  int lane = gid & 63, nt = (gid >> 6) & 15, ktg = gid >> 10;
  const float* M; int Kact, ktl;
  if (ktg < 4)       { M = W1; Kact = EMBD;  ktl = ktg;      }
  else if (ktg < 12) { M = U1; Kact = UNITS; ktl = ktg - 4;  }
  else if (ktg < 20) { M = W2; Kact = UNITS; ktl = ktg - 12; }
  else               { M = U2; Kact = UNITS; ktl = ktg - 20; }
  int n = nt * 16 + (lane & 15);
  int kb = ktl * 32 + (lane >> 4) * 8;
  size_t base = fidx(ktg, nt, lane);
#pragma unroll
  for (int j = 0; j < 8; ++j) {
    int k = kb + j;
    wf[base + j] = (f16)((k < Kact) ? M[(size_t)k * UNITS + n] : 0.f);  // RNE
  }
}

// ---------------- precompute: P1[v][n] = b1[n] + emb[v,:] @ W1 (f32 math) --
__global__ __launch_bounds__(256) void k_p1(
    const float* __restrict__ emb, const float* __restrict__ W1,
    const float* __restrict__ b1, f16* __restrict__ p1t)
{
  __shared__ float er[16][EMBD];
  const int v0 = blockIdx.x * 16;
  for (int i = threadIdx.x; i < 16 * EMBD; i += 256) {
    int vv = i / EMBD, kk = i - vv * EMBD;
    er[vv][kk] = emb[(size_t)(v0 + vv) * EMBD + kk];
  }
  __syncthreads();
  const int n = threadIdx.x;
  float acc[16];
  const float bb = b1[n];
#pragma unroll
  for (int vv = 0; vv < 16; ++vv) acc[vv] = bb;
  for (int k = 0; k < EMBD; ++k) {
    float w = W1[(size_t)k * UNITS + n];
#pragma unroll
    for (int vv = 0; vv < 16; ++vv) acc[vv] += er[vv][k] * w;
  }
#pragma unroll
  for (int vv = 0; vv < 16; ++vv)
    p1t[(size_t)(v0 + vv) * UNITS + n] = (f16)acc[vv];
}

#define MFMA16(A, B, C) __builtin_amdgcn_mfma_f32_16x16x32_f16(A, B, C, 0, 0, 0)

// store 4 consecutive-n f16 of the next-step A-frag in ONE b64 write.
// A-frag element (batch=m, k=n) lives at (n>>5)*512 + (((n>>3)&3)*16+m)*8
// + (n&7); for nb multiple of 4, the 4 targets are consecutive (8B-aligned).
__device__ __forceinline__ void store_row4(f16* __restrict__ f, int nb, int m,
                                           float v0, float v1, float v2, float v3) {
  int a = (nb >> 5) * 512 + (((nb >> 3) & 3) * 16 + m) * 8 + (nb & 7);
  h4 p; p[0] = (f16)v0; p[1] = (f16)v1; p[2] = (f16)v2; p[3] = (f16)v3;
  *(h4*)&f[a] = p;
}

#define P1S 264   // p1s row stride in f16: 528B; b64 reads ~4-way max

// ---------------------------------------------------------------------------
// Main kernel v18: 512 thr = 8 waves (2/SIMD), wave w owns n-tiles 2w, 2w+1.
// SWAPPED-OPERAND MFMA: D = MFMA(Wfrag, hfrag) = (h@W)^T; lane holds
// (n = tilebase + q*4 + r, batch = m). Iter i computes h1[i] and h2[i-1];
// one lgkm-only barrier/iter; compile-time buffer indices.
// Pinned: U1(a,b) W2(a,b) U2(a) = 160 regs.  U2(b): global/L2, loaded at
// use point (scheduler keeps ~2-3 frags live).
// ---------------------------------------------------------------------------
__global__ __launch_bounds__(512, 2)
__attribute__((amdgpu_waves_per_eu(2, 2)))
void rnn_wsE(
    const int* __restrict__ idx, const f16* __restrict__ p1t,
    const f16* __restrict__ wf, const float* __restrict__ b2,
    float* __restrict__ out)
{
  __shared__ __align__(16) f16 f1[2][4096];      // [buf][kt*512 + lane*8 + j]
  __shared__ __align__(16) f16 f2[2][4096];
  __shared__ __align__(16) f16 p1s[2][16 * P1S]; // [buf][row=batch][col=n]

  const int tid  = threadIdx.x;
  const int lane = tid & 63;
  const int w    = tid >> 6;          // wave 0..7 -> n-tiles 2w, 2w+1
  const int m    = lane & 15;         // batch row this lane accumulates
  const int q    = lane >> 4;
  const int b0   = blockIdx.x * 16;
  const int n0b  = 32 * w + 4 * q;    // 4-col group base, tile 2w
  const int n1b  = n0b + 16;          // tile 2w+1

  // bias: 4 consecutive n per tile (16B-aligned)
  const f32x4 b2v0 = *(const f32x4*)&b2[n0b];
  const f32x4 b2v1 = *(const f32x4*)&b2[n1b];

  // P1 staging assignment: thread covers 16B of row srow at offset spart*16B
  const int srow = tid >> 5, spart = tid & 31;
  const int* tokp = idx + (size_t)(b0 + srow) * TLEN;
  const f16* __restrict__ p1g = p1t + spart * 8;     // hoisted gather base
  // U2 odd-tile frag base for this (w, lane); frag kt at +kt*8192 f16
  const f16* __restrict__ u2g = wf + fidx(20, 2 * w + 1, lane);

  // -------- persistent weight fragments: U1(a,b), W2(a,b), U2(a) -----------
  // (bytes unchanged: a W B-frag IS the A-frag of W^T)
  h8 Bu1a[8], Bu1b[8], Bw2a[8], Bw2b[8], Bu2a[8];
#pragma unroll
  for (int kt = 0; kt < 8; ++kt) {
    Bu1a[kt] = *(const h8*)(wf + fidx(4 + kt, 2 * w, lane));
    Bu1b[kt] = *(const h8*)(wf + fidx(4 + kt, 2 * w + 1, lane));
    Bw2a[kt] = *(const h8*)(wf + fidx(12 + kt, 2 * w, lane));
    Bw2b[kt] = *(const h8*)(wf + fidx(12 + kt, 2 * w + 1, lane));
    Bu2a[kt] = *(const h8*)(wf + fidx(20 + kt, 2 * w, lane));
  }
  // pin ("+v", proven spill-free at exactly this 160-reg footprint)
#pragma unroll
  for (int kt = 0; kt < 8; ++kt) {
    asm volatile("" : "+v"(Bu1a[kt])); asm volatile("" : "+v"(Bu1b[kt]));
    asm volatile("" : "+v"(Bw2a[kt])); asm volatile("" : "+v"(Bw2b[kt]));
    asm volatile("" : "+v"(Bu2a[kt]));
  }

  // -------- zero h2[-1] state (f2[0]); f1[0] fully written by the peel -----
  for (int i = tid; i < 4096; i += 512) f2[0][i] = (f16)0.f;

  // -------- peel i=0: h1[0] = tanh(P1[0]) — b64 gather, b64 frag write -----
  {
    int tk = idx[(size_t)(b0 + m) * TLEN + 0];
    const f16* pr = p1t + (size_t)tk * UNITS;
    h4 v0 = *(const h4*)(pr + n0b);
    h4 v1 = *(const h4*)(pr + n1b);
    store_row4(f1[0], n0b, m, fast_tanh((float)v0[0]), fast_tanh((float)v0[1]),
                              fast_tanh((float)v0[2]), fast_tanh((float)v0[3]));
    store_row4(f1[0], n1b, m, fast_tanh((float)v1[0]), fast_tanh((float)v1[1]),
                              fast_tanh((float)v1[2]), fast_tanh((float)v1[3]));
  }

  // -------- stage P1[1] into p1s[1]; prime token pipeline ------------------
  {
    int tk1 = tokp[1];
    h8 v = *(const h8*)(p1g + (size_t)tk1 * UNITS);
    *(h8*)&p1s[1][srow * P1S + spart * 8] = v;
  }
  int tkn = tokp[2];                   // token for iter1's stage of P1[2]
  __syncthreads();   // full barrier once: f2 zero, peel, p1s[1]

  // ======== one pipelined step; RD/WR are COMPILE-TIME 0/1 =================
  // Reads f1[RD], f2[RD], p1s[WR]; writes f1[WR], f2[WR], p1s[RD].
  // Single y chain per tile: y = b2 + interleaved W2/U2 terms (f32 order
  // change only). ub frag loaded at use point -> low live range.
#define RNN_STEP(RD, WR, STAGE, TKI)                                         \
  {                                                                          \
    h8 p1v;                                                                  \
    if (STAGE) p1v = *(const h8*)(p1g + (size_t)tkn * UNITS);                \
    tkn = tokp[TKI];                                                         \
    h4 pA = *(const h4*)&p1s[WR][m * P1S + n0b];                             \
    h4 pB = *(const h4*)&p1s[WR][m * P1S + n1b];                             \
    f32x4 x0, x1;                                                            \
    _Pragma("unroll")                                                        \
    for (int r = 0; r < 4; ++r) {                                            \
      x0[r] = (float)pA[r];                                                  \
      x1[r] = (float)pB[r];                                                  \
    }                                                                        \
    f32x4 y0 = b2v0, y1 = b2v1;                                              \
    _Pragma("unroll")                                                        \
    for (int kt = 0; kt < 8; ++kt) {                                         \
      h8 a1 = *(const h8*)&f1[RD][kt * 512 + lane * 8];                      \
      h8 a2 = *(const h8*)&f2[RD][kt * 512 + lane * 8];                      \
      h8 ubk = *(const h8*)(u2g + kt * 8192);    /* L2-hot, use-point load */\
      x0 = MFMA16(Bu1a[kt], a1, x0);                                         \
      x1 = MFMA16(Bu1b[kt], a1, x1);                                         \
      y0 = MFMA16(Bw2a[kt], a1, y0);                                         \
      y1 = MFMA16(Bw2b[kt], a1, y1);                                         \
      y0 = MFMA16(Bu2a[kt], a2, y0);                                         \
      y1 = MFMA16(ubk,      a2, y1);                                         \
    }                                                                        \
    store_row4(f1[WR], n0b, m, fast_tanh(x0[0]), fast_tanh(x0[1]),           \
                               fast_tanh(x0[2]), fast_tanh(x0[3]));          \
    store_row4(f1[WR], n1b, m, fast_tanh(x1[0]), fast_tanh(x1[1]),           \
                               fast_tanh(x1[2]), fast_tanh(x1[3]));          \
    store_row4(f2[WR], n0b, m, fast_tanh(y0[0]), fast_tanh(y0[1]),           \
                               fast_tanh(y0[2]), fast_tanh(y0[3]));          \
    store_row4(f2[WR], n1b, m, fast_tanh(y1[0]), fast_tanh(y1[1]),           \
                               fast_tanh(y1[2]), fast_tanh(y1[3]));          \
    if (STAGE) *(h8*)&p1s[RD][srow * P1S + spart * 8] = p1v;                 \
    block_sync_lds();                                                        \
  }

  // -------- main loop: 39 pairs cover i = 1..78; i = 79 peeled -------------
  for (int i = 1; i < TLEN - 1; i += 2) {
    int t2 = i + 3 < TLEN - 1 ? i + 3 : TLEN - 1;   // clamp (last pair only)
    RNN_STEP(0, 1, true, i + 2);    // i odd:  reads buf0, writes buf1
    RNN_STEP(1, 0, true, t2);       // i+1:    reads buf1, writes buf0
  }
  RNN_STEP(0, 1, false, TLEN - 1);  // i = 79: no staging (tkn load harmless)
#undef RNN_STEP

  // -------- tail: h2[79] = tanh(b2 + h1[79]@W2 + h2[78]@U2) -> out ---------
  {
    f32x4 y0 = b2v0, y1 = b2v1;
#pragma unroll
    for (int kt = 0; kt < 8; ++kt) {
      h8 a1 = *(const h8*)&f1[1][kt * 512 + lane * 8];   // h1[79]
      h8 a2 = *(const h8*)&f2[1][kt * 512 + lane * 8];   // h2[78]
      h8 ubk = *(const h8*)(u2g + kt * 8192);
      y0 = MFMA16(Bw2a[kt], a1, y0);
      y1 = MFMA16(Bw2b[kt], a1, y1);
      y0 = MFMA16(Bu2a[kt], a2, y0);
      y1 = MFMA16(ubk,      a2, y1);
    }
    f32x4 o0, o1;
#pragma unroll
    for (int r = 0; r < 4; ++r) {
      o0[r] = fast_sigmoid(fast_tanh(y0[r]));
      o1[r] = fast_sigmoid(fast_tanh(y1[r]));
    }
    *(f32x4*)&out[(size_t)(b0 + m) * UNITS + n0b] = o0;
    *(f32x4*)&out[(size_t)(b0 + m) * UNITS + n1b] = o1;
  }
}

// ---------------------------------------------------------------------------
extern "C" void kernel_launch(void* const* d_in, const int* in_sizes, int n_in,
                              void* d_out, int out_size, void* d_ws, size_t ws_size,
                              hipStream_t stream)
{
  const int*   idx = (const int*)d_in[0];
  const float* emb = (const float*)d_in[1];
  const float* W1  = (const float*)d_in[2];
  const float* U1  = (const float*)d_in[3];
  const float* b1  = (const float*)d_in[4];
  const float* W2  = (const float*)d_in[5];
  const float* U2  = (const float*)d_in[6];
  const float* b2  = (const float*)d_in[7];
  // d_in[8] (Wd), d_in[9] (bd) dead in the reference output.
  float* out = (float*)d_out;

  f16* p1t = (f16*)((char*)d_ws + OFF_P1);
  f16* wf  = (f16*)((char*)d_ws + OFF_WF);
  k_p1<<<10000 / 16, 256, 0, stream>>>(emb, W1, b1, p1t);
  k_split_w16<<<(KT_ALL * 16 * 64 + 255) / 256, 256, 0, stream>>>(W1, U1, W2, U2, wf);
  rnn_wsE<<<BATCH / 16, 512, 0, stream>>>(idx, p1t, wf, b2, out);
}

// Round 14
// 222.578 us; speedup vs baseline: 1.1550x; 1.1550x over previous
//
#include <hip/hip_runtime.h>

// Problem: VOCAB=10000, EMB=100, T=80, UNITS=256, BATCH=4096 — ALL FP32 I/O.
// out = sigmoid(h2_T);  h_l,t = tanh(x_l,t @ Wl + h_l,t-1 @ Ul + bl)
//
// v19 theory (from v18 counters): u2b-to-global failed TWICE independently
// (v16 forced-live ub[8]: WRITE 18MB; v18 use-point loads: WRITE 9.7MB,
// 197us) => structural law: at 2 waves/SIMD, spill-free requires near-zero
// in-loop VMEM footprint and pinned+transient <= ~200 regs. u2b stays on
// LDS (v17 arrangement). v19 = EXACT v17 revert (145.8us verified:
// swapped-operand MFMA, 160-reg "+v" pin U1+W2+U2a, u2b in 64KB dynamic
// LDS, lgkm-only barrier, P1 b128 staging, rcp-tanh, b64 frag writes)
// + ONE delta: s_setprio(1)/(0) around the MFMA cluster (T5: favors the
// wave entering MFMA over its SIMD-mate in tanh/staging phase — the only
// unexplored in-structure lever for the ~1500cy/iter scheduling slack).
// Tripwire: WRITE_SIZE must stay 4.1 MB.
#define BATCH 4096
#define TLEN  80
#define EMBD  100
#define UNITS 256

typedef _Float16 f16;
typedef __attribute__((ext_vector_type(8))) _Float16 h8;   // 8 f16 = 4 VGPR MFMA A/B frag
typedef __attribute__((ext_vector_type(4))) _Float16 h4;   // 4 f16 = b64
typedef __attribute__((ext_vector_type(4))) float f32x4;   // MFMA C/D frag

// tanh(x) = sign(x) * (1-e)/(1+e), e = exp(-2|x|) in (0,1].
__device__ __forceinline__ float fast_tanh(float x) {
  float ax = __builtin_fabsf(x);
  float e  = __expf(-2.f * ax);
  float r  = (1.f - e) * __builtin_amdgcn_rcpf(1.f + e);
  return __builtin_copysignf(r, x);
}
// sigmoid(x) = rcp(1 + exp(-x)); saturates correctly at both ends.
__device__ __forceinline__ float fast_sigmoid(float x) {
  return __builtin_amdgcn_rcpf(1.f + __expf(-x));
}

// LDS-only barrier: all prior LDS ops visible, but vmcnt NOT drained.
__device__ __forceinline__ void block_sync_lds() {
  asm volatile("s_waitcnt lgkmcnt(0)\n\ts_barrier" ::: "memory");
}

// ---------------- workspace layout (5.58 MB <= 6.04 MB proven available) ---
// P1 table: 10000 x 256 f16 = 5,120,000 B.  wf frags: 458,752 B.
// B-frag layout (16x16x32, r7-verified): lane holds B[k=quad*8+j][n=lane&15].
// ktg slots: W1 = 0..3 (unused by main), U1 = 4..11, W2 = 12..19, U2 = 20..27.
#define KT_ALL 28
#define OFF_P1 ((size_t)0)
#define P1_BYTES ((size_t)10000 * UNITS * 2)                // 5,120,000
#define OFF_WF  P1_BYTES
#define WF_BYTES ((size_t)KT_ALL * 16 * 64 * 8 * 2)         //   458,752
#define WS_NEED (OFF_WF + WF_BYTES)                          // 5,578,752 B

__device__ __forceinline__ size_t fidx(int ktg, int nt, int lane) {
  return (((size_t)ktg * 16 + nt) * 64 + lane) * 8;
}

// ---------------- precompute: weights -> swizzled fp16 B-frags (r10-verified)
__global__ __launch_bounds__(256) void k_split_w16(
    const float* __restrict__ W1, const float* __restrict__ U1,
    const float* __restrict__ W2, const float* __restrict__ U2,
    f16* __restrict__ wf)
{
  int gid = blockIdx.x * 256 + threadIdx.x;           // one per (ktg,nt,lane)
  if (gid >= KT_ALL * 16 * 64) return;
  int lane = gid & 63, nt = (gid >> 6) & 15, ktg = gid >> 10;
  const float* M; int Kact, ktl;
  if (ktg < 4)       { M = W1; Kact = EMBD;  ktl = ktg;      }
  else if (ktg < 12) { M = U1; Kact = UNITS; ktl = ktg - 4;  }
  else if (ktg < 20) { M = W2; Kact = UNITS; ktl = ktg - 12; }
  else               { M = U2; Kact = UNITS; ktl = ktg - 20; }
  int n = nt * 16 + (lane & 15);
  int kb = ktl * 32 + (lane >> 4) * 8;
  size_t base = fidx(ktg, nt, lane);
#pragma unroll
  for (int j = 0; j < 8; ++j) {
    int k = kb + j;
    wf[base + j] = (f16)((k < Kact) ? M[(size_t)k * UNITS + n] : 0.f);  // RNE
  }
}

// ---------------- precompute: P1[v][n] = b1[n] + emb[v,:] @ W1 (f32 math) --
__global__ __launch_bounds__(256) void k_p1(
    const float* __restrict__ emb, const float* __restrict__ W1,
    const float* __restrict__ b1, f16* __restrict__ p1t)
{
  __shared__ float er[16][EMBD];
  const int v0 = blockIdx.x * 16;
  for (int i = threadIdx.x; i < 16 * EMBD; i += 256) {
    int vv = i / EMBD, kk = i - vv * EMBD;
    er[vv][kk] = emb[(size_t)(v0 + vv) * EMBD + kk];
  }
  __syncthreads();
  const int n = threadIdx.x;
  float acc[16];
  const float bb = b1[n];
#pragma unroll
  for (int vv = 0; vv < 16; ++vv) acc[vv] = bb;
  for (int k = 0; k < EMBD; ++k) {
    float w = W1[(size_t)k * UNITS + n];
#pragma unroll
    for (int vv = 0; vv < 16; ++vv) acc[vv] += er[vv][k] * w;
  }
#pragma unroll
  for (int vv = 0; vv < 16; ++vv)
    p1t[(size_t)(v0 + vv) * UNITS + n] = (f16)acc[vv];
}

#define MFMA16(A, B, C) __builtin_amdgcn_mfma_f32_16x16x32_f16(A, B, C, 0, 0, 0)

// store 4 consecutive-n f16 of the next-step A-frag in ONE b64 write.
// A-frag element (batch=m, k=n) lives at (n>>5)*512 + (((n>>3)&3)*16+m)*8
// + (n&7); for nb multiple of 4, the 4 targets are consecutive (8B-aligned).
__device__ __forceinline__ void store_row4(f16* __restrict__ f, int nb, int m,
                                           float v0, float v1, float v2, float v3) {
  int a = (nb >> 5) * 512 + (((nb >> 3) & 3) * 16 + m) * 8 + (nb & 7);
  h4 p; p[0] = (f16)v0; p[1] = (f16)v1; p[2] = (f16)v2; p[3] = (f16)v3;
  *(h4*)&f[a] = p;
}

#define P1S 264   // p1s row stride in f16: 528B; b64 reads ~4-way max

// ---------------------------------------------------------------------------
// Main kernel v19: 512 thr = 8 waves (2/SIMD), wave w owns n-tiles 2w, 2w+1.
// SWAPPED-OPERAND MFMA: D = MFMA(Wfrag, hfrag) = (h@W)^T; lane holds
// (n = tilebase + q*4 + r, batch = m). Iter i computes h1[i] and h2[i-1];
// one lgkm-only barrier/iter; compile-time buffer indices.
// Pinned: U1(a,b) W2(a,b) U2(a) = 160 regs.  U2(b): 64 KB dynamic LDS.
// s_setprio(1) around the MFMA cluster (T5).
// ---------------------------------------------------------------------------
__global__ __launch_bounds__(512, 2)
__attribute__((amdgpu_waves_per_eu(2, 2)))
void rnn_wsF(
    const int* __restrict__ idx, const f16* __restrict__ p1t,
    const f16* __restrict__ wf, const float* __restrict__ b2,
    float* __restrict__ out)
{
  __shared__ __align__(16) f16 f1[2][4096];      // [buf][kt*512 + lane*8 + j]
  __shared__ __align__(16) f16 f2[2][4096];
  __shared__ __align__(16) f16 p1s[2][16 * P1S]; // [buf][row=batch][col=n]
  extern __shared__ f16 u2s[];                   // 64 KB: odd tiles of U2

  const int tid  = threadIdx.x;
  const int lane = tid & 63;
  const int w    = tid >> 6;          // wave 0..7 -> n-tiles 2w, 2w+1
  const int m    = lane & 15;         // batch row this lane accumulates
  const int q    = lane >> 4;
  const int b0   = blockIdx.x * 16;
  const int n0b  = 32 * w + 4 * q;    // 4-col group base, tile 2w
  const int n1b  = n0b + 16;          // tile 2w+1

  // bias: 4 consecutive n per tile (16B-aligned)
  const f32x4 b2v0 = *(const f32x4*)&b2[n0b];
  const f32x4 b2v1 = *(const f32x4*)&b2[n1b];

  // P1 staging assignment: thread covers 16B of row srow at offset spart*16B
  const int srow = tid >> 5, spart = tid & 31;
  const int* tokp = idx + (size_t)(b0 + srow) * TLEN;
  const f16* __restrict__ p1g = p1t + spart * 8;     // hoisted gather base

  // -------- stage U2 odd tiles into LDS (64 KB / 512 thr = 8 h8 each) -----
  for (int d = tid; d < 4096; d += 512) {        // d = (no*8+kt)*64 + l
    int l = d & 63, g = d >> 6, no = g >> 3, kt = g & 7;
    *(h8*)&u2s[(size_t)d * 8] = *(const h8*)(wf + fidx(20 + kt, 2 * no + 1, l));
  }

  // -------- persistent weight fragments: U1(a,b), W2(a,b), U2(a) -----------
  // (bytes unchanged: a W B-frag IS the A-frag of W^T)
  h8 Bu1a[8], Bu1b[8], Bw2a[8], Bw2b[8], Bu2a[8];
#pragma unroll
  for (int kt = 0; kt < 8; ++kt) {
    Bu1a[kt] = *(const h8*)(wf + fidx(4 + kt, 2 * w, lane));
    Bu1b[kt] = *(const h8*)(wf + fidx(4 + kt, 2 * w + 1, lane));
    Bw2a[kt] = *(const h8*)(wf + fidx(12 + kt, 2 * w, lane));
    Bw2b[kt] = *(const h8*)(wf + fidx(12 + kt, 2 * w + 1, lane));
    Bu2a[kt] = *(const h8*)(wf + fidx(20 + kt, 2 * w, lane));
  }
  // pin ("+v", proven spill-free at exactly this 160-reg footprint)
#pragma unroll
  for (int kt = 0; kt < 8; ++kt) {
    asm volatile("" : "+v"(Bu1a[kt])); asm volatile("" : "+v"(Bu1b[kt]));
    asm volatile("" : "+v"(Bw2a[kt])); asm volatile("" : "+v"(Bw2b[kt]));
    asm volatile("" : "+v"(Bu2a[kt]));
  }

  // -------- zero h2[-1] state (f2[0]); f1[0] fully written by the peel -----
  for (int i = tid; i < 4096; i += 512) f2[0][i] = (f16)0.f;

  // -------- peel i=0: h1[0] = tanh(P1[0]) — b64 gather, b64 frag write -----
  {
    int tk = idx[(size_t)(b0 + m) * TLEN + 0];
    const f16* pr = p1t + (size_t)tk * UNITS;
    h4 v0 = *(const h4*)(pr + n0b);
    h4 v1 = *(const h4*)(pr + n1b);
    store_row4(f1[0], n0b, m, fast_tanh((float)v0[0]), fast_tanh((float)v0[1]),
                              fast_tanh((float)v0[2]), fast_tanh((float)v0[3]));
    store_row4(f1[0], n1b, m, fast_tanh((float)v1[0]), fast_tanh((float)v1[1]),
                              fast_tanh((float)v1[2]), fast_tanh((float)v1[3]));
  }

  // -------- stage P1[1] into p1s[1]; prime token pipeline ------------------
  {
    int tk1 = tokp[1];
    h8 v = *(const h8*)(p1g + (size_t)tk1 * UNITS);
    *(h8*)&p1s[1][srow * P1S + spart * 8] = v;
  }
  int tkn = tokp[2];                   // token for iter1's stage of P1[2]
  __syncthreads();   // full barrier once: u2s, f2 zero, peel, p1s[1]

  // ======== one pipelined step; RD/WR are COMPILE-TIME 0/1 =================
  // Reads f1[RD], f2[RD], p1s[WR]; writes f1[WR], f2[WR], p1s[RD].
#define RNN_STEP(RD, WR, STAGE, TKI)                                         \
  {                                                                          \
    h8 p1v;                                                                  \
    if (STAGE) p1v = *(const h8*)(p1g + (size_t)tkn * UNITS);                \
    tkn = tokp[TKI];                                                         \
    h4 pA = *(const h4*)&p1s[WR][m * P1S + n0b];                             \
    h4 pB = *(const h4*)&p1s[WR][m * P1S + n1b];                             \
    f32x4 x0, x1;                                                            \
    _Pragma("unroll")                                                        \
    for (int r = 0; r < 4; ++r) {                                            \
      x0[r] = (float)pA[r];                                                  \
      x1[r] = (float)pB[r];                                                  \
    }                                                                        \
    f32x4 yA0 = b2v0, yA1 = b2v1;                                            \
    f32x4 yB0 = (f32x4){0.f, 0.f, 0.f, 0.f};                                 \
    f32x4 yB1 = (f32x4){0.f, 0.f, 0.f, 0.f};                                 \
    __builtin_amdgcn_s_setprio(1);                                           \
    _Pragma("unroll")                                                        \
    for (int kt = 0; kt < 8; ++kt) {                                         \
      h8 a1 = *(const h8*)&f1[RD][kt * 512 + lane * 8];                      \
      h8 a2 = *(const h8*)&f2[RD][kt * 512 + lane * 8];                      \
      h8 ub = *(const h8*)&u2s[((w * 8 + kt) * 64 + lane) * 8];              \
      x0  = MFMA16(Bu1a[kt], a1, x0);                                        \
      x1  = MFMA16(Bu1b[kt], a1, x1);                                        \
      yA0 = MFMA16(Bw2a[kt], a1, yA0);                                       \
      yA1 = MFMA16(Bw2b[kt], a1, yA1);                                       \
      yB0 = MFMA16(Bu2a[kt], a2, yB0);                                       \
      yB1 = MFMA16(ub,       a2, yB1);                                       \
    }                                                                        \
    __builtin_amdgcn_s_setprio(0);                                           \
    store_row4(f1[WR], n0b, m, fast_tanh(x0[0]), fast_tanh(x0[1]),           \
                               fast_tanh(x0[2]), fast_tanh(x0[3]));          \
    store_row4(f1[WR], n1b, m, fast_tanh(x1[0]), fast_tanh(x1[1]),           \
                               fast_tanh(x1[2]), fast_tanh(x1[3]));          \
    store_row4(f2[WR], n0b, m,                                               \
               fast_tanh(yA0[0] + yB0[0]), fast_tanh(yA0[1] + yB0[1]),       \
               fast_tanh(yA0[2] + yB0[2]), fast_tanh(yA0[3] + yB0[3]));      \
    store_row4(f2[WR], n1b, m,                                               \
               fast_tanh(yA1[0] + yB1[0]), fast_tanh(yA1[1] + yB1[1]),       \
               fast_tanh(yA1[2] + yB1[2]), fast_tanh(yA1[3] + yB1[3]));      \
    if (STAGE) *(h8*)&p1s[RD][srow * P1S + spart * 8] = p1v;                 \
    block_sync_lds();                                                        \
  }

  // -------- main loop: 39 pairs cover i = 1..78; i = 79 peeled -------------
  for (int i = 1; i < TLEN - 1; i += 2) {
    int t2 = i + 3 < TLEN - 1 ? i + 3 : TLEN - 1;   // clamp (last pair only)
    RNN_STEP(0, 1, true, i + 2);    // i odd:  reads buf0, writes buf1
    RNN_STEP(1, 0, true, t2);       // i+1:    reads buf1, writes buf0
  }
  RNN_STEP(0, 1, false, TLEN - 1);  // i = 79: no staging (tkn load harmless)
#undef RNN_STEP

  // -------- tail: h2[79] = tanh(b2 + h1[79]@W2 + h2[78]@U2) -> out ---------
  {
    f32x4 yA0 = b2v0, yA1 = b2v1;
    f32x4 yB0 = (f32x4){0.f, 0.f, 0.f, 0.f};
    f32x4 yB1 = (f32x4){0.f, 0.f, 0.f, 0.f};
#pragma unroll
    for (int kt = 0; kt < 8; ++kt) {
      h8 a1 = *(const h8*)&f1[1][kt * 512 + lane * 8];   // h1[79]
      h8 a2 = *(const h8*)&f2[1][kt * 512 + lane * 8];   // h2[78]
      h8 ub = *(const h8*)&u2s[((w * 8 + kt) * 64 + lane) * 8];
      yA0 = MFMA16(Bw2a[kt], a1, yA0);
      yA1 = MFMA16(Bw2b[kt], a1, yA1);
      yB0 = MFMA16(Bu2a[kt], a2, yB0);
      yB1 = MFMA16(ub,       a2, yB1);
    }
    f32x4 o0, o1;
#pragma unroll
    for (int r = 0; r < 4; ++r) {
      o0[r] = fast_sigmoid(fast_tanh(yA0[r] + yB0[r]));
      o1[r] = fast_sigmoid(fast_tanh(yA1[r] + yB1[r]));
    }
    *(f32x4*)&out[(size_t)(b0 + m) * UNITS + n0b] = o0;
    *(f32x4*)&out[(size_t)(b0 + m) * UNITS + n1b] = o1;
  }
}

// ---------------------------------------------------------------------------
extern "C" void kernel_launch(void* const* d_in, const int* in_sizes, int n_in,
                              void* d_out, int out_size, void* d_ws, size_t ws_size,
                              hipStream_t stream)
{
  const int*   idx = (const int*)d_in[0];
  const float* emb = (const float*)d_in[1];
  const float* W1  = (const float*)d_in[2];
  const float* U1  = (const float*)d_in[3];
  const float* b1  = (const float*)d_in[4];
  const float* W2  = (const float*)d_in[5];
  const float* U2  = (const float*)d_in[6];
  const float* b2  = (const float*)d_in[7];
  // d_in[8] (Wd), d_in[9] (bd) dead in the reference output.
  float* out = (float*)d_out;

  // 64 KB dynamic + ~48.5 KB static ≈ 114 KB LDS/workgroup -> 1 block/CU.
  static bool attr_done = false;
  if (!attr_done) {
    (void)hipFuncSetAttribute((const void*)rnn_wsF,
                              hipFuncAttributeMaxDynamicSharedMemorySize,
                              65536);
    attr_done = true;
  }

  f16* p1t = (f16*)((char*)d_ws + OFF_P1);
  f16* wf  = (f16*)((char*)d_ws + OFF_WF);
  k_p1<<<10000 / 16, 256, 0, stream>>>(emb, W1, b1, p1t);
  k_split_w16<<<(KT_ALL * 16 * 64 + 255) / 256, 256, 0, stream>>>(W1, U1, W2, U2, wf);
  rnn_wsF<<<BATCH / 16, 512, 65536, stream>>>(idx, p1t, wf, b2, out);
}

// Round 15
// 218.744 us; speedup vs baseline: 1.1752x; 1.0175x over previous
//
#include <hip/hip_runtime.h>

// Problem: VOCAB=10000, EMB=100, T=80, UNITS=256, BATCH=4096 — ALL FP32 I/O.
// out = sigmoid(h2_T);  h_l,t = tanh(x_l,t @ Wl + h_l,t-1 @ Ul + bl)
//
// v20 theory (from v19 counters): setprio = -4% (lockstep waves, no role
// diversity -> T5 null, reverted). v17 (145.8us) is the verified base.
// Remaining clean LDS cut: the swapped layout makes p1s staging obsolete —
// each lane needs P1 at 4 CONSECUTIVE n for ONE batch row = 2 x b64 global
// loads straight to registers (wave = 16 rows x 64 contiguous B, L2-hot).
// Deletes per-wave-iter 1 ds_write_b128 + 2 ds_read_b64 (~225 cy/CU-iter
// LDS) + 8.4 KB LDS. Gather prefetched one iter ahead in registers
// (pv0/pv1 + token pipeline) so L2 latency hides under the MFMA chains,
// and the lgkm-only barrier never drains it. (v12's scalar-gather failure
// was 12 scattered 2B loads/lane in the UNswapped layout — not this.)
// Rest byte-identical to v17: swapped-operand MFMA, 160-reg "+v" pin
// (U1 a,b / W2 a,b / U2 a), u2b in 64KB dynamic LDS, lgkm-only barrier,
// rcp-tanh, b64 frag writes, compile-time buffer indices.
// Tripwire: WRITE_SIZE must stay 4.1 MB.
#define BATCH 4096
#define TLEN  80
#define EMBD  100
#define UNITS 256

typedef _Float16 f16;
typedef __attribute__((ext_vector_type(8))) _Float16 h8;   // 8 f16 = 4 VGPR MFMA A/B frag
typedef __attribute__((ext_vector_type(4))) _Float16 h4;   // 4 f16 = b64
typedef __attribute__((ext_vector_type(4))) float f32x4;   // MFMA C/D frag

// tanh(x) = sign(x) * (1-e)/(1+e), e = exp(-2|x|) in (0,1].
__device__ __forceinline__ float fast_tanh(float x) {
  float ax = __builtin_fabsf(x);
  float e  = __expf(-2.f * ax);
  float r  = (1.f - e) * __builtin_amdgcn_rcpf(1.f + e);
  return __builtin_copysignf(r, x);
}
// sigmoid(x) = rcp(1 + exp(-x)); saturates correctly at both ends.
__device__ __forceinline__ float fast_sigmoid(float x) {
  return __builtin_amdgcn_rcpf(1.f + __expf(-x));
}

// LDS-only barrier: all prior LDS ops visible, but vmcnt NOT drained.
__device__ __forceinline__ void block_sync_lds() {
  asm volatile("s_waitcnt lgkmcnt(0)\n\ts_barrier" ::: "memory");
}

// ---------------- workspace layout (5.58 MB <= 6.04 MB proven available) ---
// P1 table: 10000 x 256 f16 = 5,120,000 B.  wf frags: 458,752 B.
// B-frag layout (16x16x32, r7-verified): lane holds B[k=quad*8+j][n=lane&15].
// ktg slots: W1 = 0..3 (unused by main), U1 = 4..11, W2 = 12..19, U2 = 20..27.
#define KT_ALL 28
#define OFF_P1 ((size_t)0)
#define P1_BYTES ((size_t)10000 * UNITS * 2)                // 5,120,000
#define OFF_WF  P1_BYTES
#define WF_BYTES ((size_t)KT_ALL * 16 * 64 * 8 * 2)         //   458,752
#define WS_NEED (OFF_WF + WF_BYTES)                          // 5,578,752 B

__device__ __forceinline__ size_t fidx(int ktg, int nt, int lane) {
  return (((size_t)ktg * 16 + nt) * 64 + lane) * 8;
}

// ---------------- precompute: weights -> swizzled fp16 B-frags (r10-verified)
__global__ __launch_bounds__(256) void k_split_w16(
    const float* __restrict__ W1, const float* __restrict__ U1,
    const float* __restrict__ W2, const float* __restrict__ U2,
    f16* __restrict__ wf)
{
  int gid = blockIdx.x * 256 + threadIdx.x;           // one per (ktg,nt,lane)
  if (gid >= KT_ALL * 16 * 64) return;
  int lane = gid & 63, nt = (gid >> 6) & 15, ktg = gid >> 10;
  const float* M; int Kact, ktl;
  if (ktg < 4)       { M = W1; Kact = EMBD;  ktl = ktg;      }
  else if (ktg < 12) { M = U1; Kact = UNITS; ktl = ktg - 4;  }
  else if (ktg < 20) { M = W2; Kact = UNITS; ktl = ktg - 12; }
  else               { M = U2; Kact = UNITS; ktl = ktg - 20; }
  int n = nt * 16 + (lane & 15);
  int kb = ktl * 32 + (lane >> 4) * 8;
  size_t base = fidx(ktg, nt, lane);
#pragma unroll
  for (int j = 0; j < 8; ++j) {
    int k = kb + j;
    wf[base + j] = (f16)((k < Kact) ? M[(size_t)k * UNITS + n] : 0.f);  // RNE
  }
}

// ---------------- precompute: P1[v][n] = b1[n] + emb[v,:] @ W1 (f32 math) --
__global__ __launch_bounds__(256) void k_p1(
    const float* __restrict__ emb, const float* __restrict__ W1,
    const float* __restrict__ b1, f16* __restrict__ p1t)
{
  __shared__ float er[16][EMBD];
  const int v0 = blockIdx.x * 16;
  for (int i = threadIdx.x; i < 16 * EMBD; i += 256) {
    int vv = i / EMBD, kk = i - vv * EMBD;
    er[vv][kk] = emb[(size_t)(v0 + vv) * EMBD + kk];
  }
  __syncthreads();
  const int n = threadIdx.x;
  float acc[16];
  const float bb = b1[n];
#pragma unroll
  for (int vv = 0; vv < 16; ++vv) acc[vv] = bb;
  for (int k = 0; k < EMBD; ++k) {
    float w = W1[(size_t)k * UNITS + n];
#pragma unroll
    for (int vv = 0; vv < 16; ++vv) acc[vv] += er[vv][k] * w;
  }
#pragma unroll
  for (int vv = 0; vv < 16; ++vv)
    p1t[(size_t)(v0 + vv) * UNITS + n] = (f16)acc[vv];
}

#define MFMA16(A, B, C) __builtin_amdgcn_mfma_f32_16x16x32_f16(A, B, C, 0, 0, 0)

// store 4 consecutive-n f16 of the next-step A-frag in ONE b64 write.
// A-frag element (batch=m, k=n) lives at (n>>5)*512 + (((n>>3)&3)*16+m)*8
// + (n&7); for nb multiple of 4, the 4 targets are consecutive (8B-aligned).
__device__ __forceinline__ void store_row4(f16* __restrict__ f, int nb, int m,
                                           float v0, float v1, float v2, float v3) {
  int a = (nb >> 5) * 512 + (((nb >> 3) & 3) * 16 + m) * 8 + (nb & 7);
  h4 p; p[0] = (f16)v0; p[1] = (f16)v1; p[2] = (f16)v2; p[3] = (f16)v3;
  *(h4*)&f[a] = p;
}

// ---------------------------------------------------------------------------
// Main kernel v20: 512 thr = 8 waves (2/SIMD), wave w owns n-tiles 2w, 2w+1.
// SWAPPED-OPERAND MFMA: D = MFMA(Wfrag, hfrag) = (h@W)^T; lane holds
// (n = tilebase + q*4 + r, batch = m). Iter i computes h1[i] and h2[i-1];
// one lgkm-only barrier/iter; compile-time buffer indices.
// Pinned: U1(a,b) W2(a,b) U2(a) = 160 regs.  U2(b): 64 KB dynamic LDS.
// P1: 2 x b64 register gather per lane, prefetched one iter ahead (no LDS).
// ---------------------------------------------------------------------------
__global__ __launch_bounds__(512, 2)
__attribute__((amdgpu_waves_per_eu(2, 2)))
void rnn_wsG(
    const int* __restrict__ idx, const f16* __restrict__ p1t,
    const f16* __restrict__ wf, const float* __restrict__ b2,
    float* __restrict__ out)
{
  __shared__ __align__(16) f16 f1[2][4096];      // [buf][kt*512 + lane*8 + j]
  __shared__ __align__(16) f16 f2[2][4096];
  extern __shared__ f16 u2s[];                   // 64 KB: odd tiles of U2

  const int tid  = threadIdx.x;
  const int lane = tid & 63;
  const int w    = tid >> 6;          // wave 0..7 -> n-tiles 2w, 2w+1
  const int m    = lane & 15;         // batch row this lane accumulates
  const int q    = lane >> 4;
  const int b0   = blockIdx.x * 16;
  const int n0b  = 32 * w + 4 * q;    // 4-col group base, tile 2w
  const int n1b  = n0b + 16;          // tile 2w+1

  // bias: 4 consecutive n per tile (16B-aligned)
  const f32x4 b2v0 = *(const f32x4*)&b2[n0b];
  const f32x4 b2v1 = *(const f32x4*)&b2[n1b];

  // per-lane token pointer (row m) and hoisted P1 gather base
  const int* tokm = idx + (size_t)(b0 + m) * TLEN;
  const f16* __restrict__ p1g = p1t + n0b;       // +tok*UNITS, +16 for n1b

  // -------- stage U2 odd tiles into LDS (64 KB / 512 thr = 8 h8 each) -----
  for (int d = tid; d < 4096; d += 512) {        // d = (no*8+kt)*64 + l
    int l = d & 63, g = d >> 6, no = g >> 3, kt = g & 7;
    *(h8*)&u2s[(size_t)d * 8] = *(const h8*)(wf + fidx(20 + kt, 2 * no + 1, l));
  }

  // -------- persistent weight fragments: U1(a,b), W2(a,b), U2(a) -----------
  // (bytes unchanged: a W B-frag IS the A-frag of W^T)
  h8 Bu1a[8], Bu1b[8], Bw2a[8], Bw2b[8], Bu2a[8];
#pragma unroll
  for (int kt = 0; kt < 8; ++kt) {
    Bu1a[kt] = *(const h8*)(wf + fidx(4 + kt, 2 * w, lane));
    Bu1b[kt] = *(const h8*)(wf + fidx(4 + kt, 2 * w + 1, lane));
    Bw2a[kt] = *(const h8*)(wf + fidx(12 + kt, 2 * w, lane));
    Bw2b[kt] = *(const h8*)(wf + fidx(12 + kt, 2 * w + 1, lane));
    Bu2a[kt] = *(const h8*)(wf + fidx(20 + kt, 2 * w, lane));
  }
  // pin ("+v", proven spill-free at exactly this 160-reg footprint)
#pragma unroll
  for (int kt = 0; kt < 8; ++kt) {
    asm volatile("" : "+v"(Bu1a[kt])); asm volatile("" : "+v"(Bu1b[kt]));
    asm volatile("" : "+v"(Bw2a[kt])); asm volatile("" : "+v"(Bw2b[kt]));
    asm volatile("" : "+v"(Bu2a[kt]));
  }

  // -------- zero h2[-1] state (f2[0]); f1[0] fully written by the peel -----
  for (int i = tid; i < 4096; i += 512) f2[0][i] = (f16)0.f;

  // -------- peel i=0: h1[0] = tanh(P1[0]) — b64 gather, b64 frag write -----
  {
    const f16* pr = p1g + (size_t)tokm[0] * UNITS;
    h4 v0 = *(const h4*)(pr);
    h4 v1 = *(const h4*)(pr + 16);
    store_row4(f1[0], n0b, m, fast_tanh((float)v0[0]), fast_tanh((float)v0[1]),
                              fast_tanh((float)v0[2]), fast_tanh((float)v0[3]));
    store_row4(f1[0], n1b, m, fast_tanh((float)v1[0]), fast_tanh((float)v1[1]),
                              fast_tanh((float)v1[2]), fast_tanh((float)v1[3]));
  }

  // -------- prime the P1 register pipeline: pv = P1[1], tkn = tok[2] -------
  h4 pv0, pv1;
  {
    const f16* pr = p1g + (size_t)tokm[1] * UNITS;
    pv0 = *(const h4*)(pr);
    pv1 = *(const h4*)(pr + 16);
  }
  int tkn = tokm[2];                   // token for iter1's prefetch of P1[2]
  __syncthreads();   // full barrier once: u2s, f2 zero, peel

  // ======== one pipelined step; RD/WR are COMPILE-TIME 0/1 =================
  // Reads f1[RD], f2[RD]; writes f1[WR], f2[WR]. P1 flows through pv0/pv1
  // registers: consume (acc init) -> immediately issue next gather -> the
  // MFMA section hides its L2 latency; lgkm barrier leaves it in flight.
#define RNN_STEP(RD, WR, STAGE, TKI)                                         \
  {                                                                          \
    f32x4 x0, x1;                                                            \
    _Pragma("unroll")                                                        \
    for (int r = 0; r < 4; ++r) {                                            \
      x0[r] = (float)pv0[r];                                                 \
      x1[r] = (float)pv1[r];                                                 \
    }                                                                        \
    if (STAGE) {                                                             \
      const f16* pr_ = p1g + (size_t)tkn * UNITS;                            \
      pv0 = *(const h4*)(pr_);                                               \
      pv1 = *(const h4*)(pr_ + 16);                                          \
    }                                                                        \
    tkn = tokm[TKI];                                                         \
    f32x4 yA0 = b2v0, yA1 = b2v1;                                            \
    f32x4 yB0 = (f32x4){0.f, 0.f, 0.f, 0.f};                                 \
    f32x4 yB1 = (f32x4){0.f, 0.f, 0.f, 0.f};                                 \
    _Pragma("unroll")                                                        \
    for (int kt = 0; kt < 8; ++kt) {                                         \
      h8 a1 = *(const h8*)&f1[RD][kt * 512 + lane * 8];                      \
      h8 a2 = *(const h8*)&f2[RD][kt * 512 + lane * 8];                      \
      h8 ub = *(const h8*)&u2s[((w * 8 + kt) * 64 + lane) * 8];              \
      x0  = MFMA16(Bu1a[kt], a1, x0);                                        \
      x1  = MFMA16(Bu1b[kt], a1, x1);                                        \
      yA0 = MFMA16(Bw2a[kt], a1, yA0);                                       \
      yA1 = MFMA16(Bw2b[kt], a1, yA1);                                       \
      yB0 = MFMA16(Bu2a[kt], a2, yB0);                                       \
      yB1 = MFMA16(ub,       a2, yB1);                                       \
    }                                                                        \
    store_row4(f1[WR], n0b, m, fast_tanh(x0[0]), fast_tanh(x0[1]),           \
                               fast_tanh(x0[2]), fast_tanh(x0[3]));          \
    store_row4(f1[WR], n1b, m, fast_tanh(x1[0]), fast_tanh(x1[1]),           \
                               fast_tanh(x1[2]), fast_tanh(x1[3]));          \
    store_row4(f2[WR], n0b, m,                                               \
               fast_tanh(yA0[0] + yB0[0]), fast_tanh(yA0[1] + yB0[1]),       \
               fast_tanh(yA0[2] + yB0[2]), fast_tanh(yA0[3] + yB0[3]));      \
    store_row4(f2[WR], n1b, m,                                               \
               fast_tanh(yA1[0] + yB1[0]), fast_tanh(yA1[1] + yB1[1]),       \
               fast_tanh(yA1[2] + yB1[2]), fast_tanh(yA1[3] + yB1[3]));      \
    block_sync_lds();                                                        \
  }

  // -------- main loop: 39 pairs cover i = 1..78; i = 79 peeled -------------
  for (int i = 1; i < TLEN - 1; i += 2) {
    int t2 = i + 3 < TLEN - 1 ? i + 3 : TLEN - 1;   // clamp (last pair only)
    RNN_STEP(0, 1, true, i + 2);    // i odd:  reads buf0, writes buf1
    RNN_STEP(1, 0, true, t2);       // i+1:    reads buf1, writes buf0
  }
  RNN_STEP(0, 1, false, TLEN - 1);  // i = 79: no prefetch (tkn load harmless)
#undef RNN_STEP

  // -------- tail: h2[79] = tanh(b2 + h1[79]@W2 + h2[78]@U2) -> out ---------
  {
    f32x4 yA0 = b2v0, yA1 = b2v1;
    f32x4 yB0 = (f32x4){0.f, 0.f, 0.f, 0.f};
    f32x4 yB1 = (f32x4){0.f, 0.f, 0.f, 0.f};
#pragma unroll
    for (int kt = 0; kt < 8; ++kt) {
      h8 a1 = *(const h8*)&f1[1][kt * 512 + lane * 8];   // h1[79]
      h8 a2 = *(const h8*)&f2[1][kt * 512 + lane * 8];   // h2[78]
      h8 ub = *(const h8*)&u2s[((w * 8 + kt) * 64 + lane) * 8];
      yA0 = MFMA16(Bw2a[kt], a1, yA0);
      yA1 = MFMA16(Bw2b[kt], a1, yA1);
      yB0 = MFMA16(Bu2a[kt], a2, yB0);
      yB1 = MFMA16(ub,       a2, yB1);
    }
    f32x4 o0, o1;
#pragma unroll
    for (int r = 0; r < 4; ++r) {
      o0[r] = fast_sigmoid(fast_tanh(yA0[r] + yB0[r]));
      o1[r] = fast_sigmoid(fast_tanh(yA1[r] + yB1[r]));
    }
    *(f32x4*)&out[(size_t)(b0 + m) * UNITS + n0b] = o0;
    *(f32x4*)&out[(size_t)(b0 + m) * UNITS + n1b] = o1;
  }
}

// ---------------------------------------------------------------------------
extern "C" void kernel_launch(void* const* d_in, const int* in_sizes, int n_in,
                              void* d_out, int out_size, void* d_ws, size_t ws_size,
                              hipStream_t stream)
{
  const int*   idx = (const int*)d_in[0];
  const float* emb = (const float*)d_in[1];
  const float* W1  = (const float*)d_in[2];
  const float* U1  = (const float*)d_in[3];
  const float* b1  = (const float*)d_in[4];
  const float* W2  = (const float*)d_in[5];
  const float* U2  = (const float*)d_in[6];
  const float* b2  = (const float*)d_in[7];
  // d_in[8] (Wd), d_in[9] (bd) dead in the reference output.
  float* out = (float*)d_out;

  // 64 KB dynamic + 32 KB static = 96 KB LDS/workgroup -> 1 block/CU.
  static bool attr_done = false;
  if (!attr_done) {
    (void)hipFuncSetAttribute((const void*)rnn_wsG,
                              hipFuncAttributeMaxDynamicSharedMemorySize,
                              65536);
    attr_done = true;
  }

  f16* p1t = (f16*)((char*)d_ws + OFF_P1);
  f16* wf  = (f16*)((char*)d_ws + OFF_WF);
  k_p1<<<10000 / 16, 256, 0, stream>>>(emb, W1, b1, p1t);
  k_split_w16<<<(KT_ALL * 16 * 64 + 255) / 256, 256, 0, stream>>>(W1, U1, W2, U2, wf);
  rnn_wsG<<<BATCH / 16, 512, 65536, stream>>>(idx, p1t, wf, b2, out);
}